// Round 2
// 521.458 us; speedup vs baseline: 1.2151x; 1.2151x over previous
//
#include <hip/hip_runtime.h>
#include <math.h>

#define Bn 64
#define Hn 1024
#define BH 65536          // Bn * Hn

// native vector type for nontemporal builtins (HIP_vector_type not accepted)
typedef float v4f __attribute__((ext_vector_type(4)));

// ws layout (floats):
//   [0      ,  6*BH) : final gates i,f,o,k,v,q      (g*BH + b*1024 + n)
//   [6*BH   , 54*BH) : gate GEMM partials, slot (g*8 + s), 8 K-splits/gate
//   [54*BH  , 70*BH) : ngate GEMM partials, 16 K-splits
// total 70*BH floats = 18.3 MB  (ws is ~1 GiB)
#define WS_GP (6 * BH)
#define WS_NP (54 * BH)

// ---------------------------------------------------------------------------
// Kernel A: partial GEMMs for the six projections.
//   grid = (16 n-tiles, 8 K-splits, 6 gates) = 768 blocks (3 blocks/CU),
//   block = 256 threads. Tile: 64 rows x 64 cols, chunk = Ktot/8 (256 or 128).
//   Thread = 4 consecutive cols (float4 weight loads) x 4 rows.
//   Per 4-k step/thread: 4 global float4 + 4 ds_read_b128 -> 64 FMAs.
// ---------------------------------------------------------------------------
__global__ __launch_bounds__(256) void gates_partial(
    const float* __restrict__ x, const float* __restrict__ h_prev,
    const float* __restrict__ Wi, const float* __restrict__ Wf,
    const float* __restrict__ Wo, const float* __restrict__ Wk,
    const float* __restrict__ Wv, const float* __restrict__ Wq,
    float* __restrict__ ws)
{
    const int g = blockIdx.z, s = blockIdx.y;
    const float* Wm;
    int Ktot;
    switch (g) {
        case 0: Wm = Wi; Ktot = 2048; break;
        case 1: Wm = Wf; Ktot = 2048; break;
        case 2: Wm = Wo; Ktot = 2048; break;
        case 3: Wm = Wk; Ktot = 1024; break;
        case 4: Wm = Wv; Ktot = 1024; break;
        default: Wm = Wq; Ktot = 1024; break;
    }
    const int chunk = Ktot >> 3;      // 256 (g<3) or 128 (g>=3)
    const int kbase = s * chunk;

    __shared__ float A_lds[64][68];   // +4 pad: 4-row-stride reads 2-way only

    const int t  = threadIdx.x;
    const int cg = t & 15;            // col group: 4 consecutive cols
    const int rg = t >> 4;            // row group 0..15: rows rg*4..rg*4+3
    const int n0 = (blockIdx.x << 6) + (cg << 2);

    float4 acc[4];
    #pragma unroll
    for (int r = 0; r < 4; ++r) acc[r] = make_float4(0.f, 0.f, 0.f, 0.f);

    for (int kc = 0; kc < chunk; kc += 64) {
        const int k0 = kbase + kc;
        const float* Ab;
        int kloc;
        if (g < 3)       { Ab = (k0 < 1024) ? x : h_prev; kloc = k0 & 1023; }
        else if (g == 5) { Ab = h_prev; kloc = k0; }
        else             { Ab = x;      kloc = k0; }

        __syncthreads();
        {   // cooperative stage: 64 rows x 64 k-cols
            const int c = cg << 2;
            #pragma unroll
            for (int rr = 0; rr < 4; ++rr) {
                const int row = rg + (rr << 4);
                *(float4*)&A_lds[row][c] =
                    *(const float4*)&Ab[(size_t)row * 1024 + kloc + c];
            }
        }
        __syncthreads();

        #pragma unroll 2
        for (int kk = 0; kk < 64; kk += 4) {
            const float* wp = Wm + (size_t)(k0 + kk) * 1024 + n0;
            const float4 w0 = *(const float4*)(wp);
            const float4 w1 = *(const float4*)(wp + 1024);
            const float4 w2 = *(const float4*)(wp + 2048);
            const float4 w3 = *(const float4*)(wp + 3072);
            #pragma unroll
            for (int r = 0; r < 4; ++r) {
                const float4 a = *(const float4*)&A_lds[(rg << 2) + r][kk];
                acc[r].x += a.x * w0.x + a.y * w1.x + a.z * w2.x + a.w * w3.x;
                acc[r].y += a.x * w0.y + a.y * w1.y + a.z * w2.y + a.w * w3.y;
                acc[r].z += a.x * w0.z + a.y * w1.z + a.z * w2.z + a.w * w3.z;
                acc[r].w += a.x * w0.w + a.y * w1.w + a.z * w2.w + a.w * w3.w;
            }
        }
    }

    float* P = ws + WS_GP + (size_t)(g * 8 + s) * BH;
    #pragma unroll
    for (int r = 0; r < 4; ++r)
        *(float4*)&P[(size_t)((rg << 2) + r) * 1024 + n0] = acc[r];
}

// ---------------------------------------------------------------------------
// Kernel B: reduce 8 K-split partials + bias (+ sigmoid for i,f,o) -> gates.
//   float4 per thread: 6*BH/4 elems / 256 = 384 blocks.
// ---------------------------------------------------------------------------
__global__ __launch_bounds__(256) void gates_finalize(
    const float* __restrict__ bi, const float* __restrict__ bf,
    const float* __restrict__ bo, const float* __restrict__ bk,
    const float* __restrict__ bv, const float* __restrict__ bq,
    float* __restrict__ ws)
{
    const int v4 = blockIdx.x * 256 + threadIdx.x;   // < 6 * 16384
    const int g  = v4 >> 14;
    const int r4 = v4 & 16383;                       // float4 idx within gate
    const float4* P = (const float4*)(ws + WS_GP + (size_t)g * 8 * BH);
    float4 a = P[r4];
    #pragma unroll
    for (int s = 1; s < 8; ++s) {
        const float4 p = P[(size_t)s * (BH / 4) + r4];
        a.x += p.x; a.y += p.y; a.z += p.z; a.w += p.w;
    }
    const float* bias;
    switch (g) {
        case 0: bias = bi; break; case 1: bias = bf; break;
        case 2: bias = bo; break; case 3: bias = bk; break;
        case 4: bias = bv; break; default: bias = bq; break;
    }
    const float4 b4 = ((const float4*)bias)[r4 & 255];
    a.x += b4.x; a.y += b4.y; a.z += b4.z; a.w += b4.w;
    if (g < 3) {
        a.x = 1.f / (1.f + expf(-a.x));
        a.y = 1.f / (1.f + expf(-a.y));
        a.z = 1.f / (1.f + expf(-a.z));
        a.w = 1.f / (1.f + expf(-a.w));
    }
    ((float4*)ws)[v4] = a;
}

// ---------------------------------------------------------------------------
// Kernel C: partials of m = k_t @ We. grid (16 n-tiles, 16 K-splits) = 256
// blocks, chunk = 64 (single stage). Same tile structure as Kernel A.
// ---------------------------------------------------------------------------
__global__ __launch_bounds__(256) void ngate_partial(
    const float* __restrict__ We, float* __restrict__ ws)
{
    const int s  = blockIdx.y;           // 0..15
    const int k0 = s * 64;
    const float* kt = ws + 3 * BH;       // finalized k from Kernel B

    __shared__ float A_lds[64][68];

    const int t  = threadIdx.x;
    const int cg = t & 15;
    const int rg = t >> 4;
    const int n0 = (blockIdx.x << 6) + (cg << 2);

    float4 acc[4];
    #pragma unroll
    for (int r = 0; r < 4; ++r) acc[r] = make_float4(0.f, 0.f, 0.f, 0.f);

    {
        const int c = cg << 2;
        #pragma unroll
        for (int rr = 0; rr < 4; ++rr) {
            const int row = rg + (rr << 4);
            *(float4*)&A_lds[row][c] =
                *(const float4*)&kt[(size_t)row * 1024 + k0 + c];
        }
    }
    __syncthreads();

    #pragma unroll 2
    for (int kk = 0; kk < 64; kk += 4) {
        const float* wp = We + (size_t)(k0 + kk) * 1024 + n0;
        const float4 w0 = *(const float4*)(wp);
        const float4 w1 = *(const float4*)(wp + 1024);
        const float4 w2 = *(const float4*)(wp + 2048);
        const float4 w3 = *(const float4*)(wp + 3072);
        #pragma unroll
        for (int r = 0; r < 4; ++r) {
            const float4 a = *(const float4*)&A_lds[(rg << 2) + r][kk];
            acc[r].x += a.x * w0.x + a.y * w1.x + a.z * w2.x + a.w * w3.x;
            acc[r].y += a.x * w0.y + a.y * w1.y + a.z * w2.y + a.w * w3.y;
            acc[r].z += a.x * w0.z + a.y * w1.z + a.z * w2.z + a.w * w3.z;
            acc[r].w += a.x * w0.w + a.y * w1.w + a.z * w2.w + a.w * w3.w;
        }
    }

    float* P = ws + WS_NP + (size_t)s * BH;
    #pragma unroll
    for (int r = 0; r < 4; ++r)
        *(float4*)&P[(size_t)((rg << 2) + r) * 1024 + n0] = acc[r];
}

// ---------------------------------------------------------------------------
// Kernel E: fused n_t + C update + h_t. One wave per 8 rows of C; all rows of
// a block share b so k,q live in registers. n_t computed in-wave from the 16
// ngate partials (wave-uniform scalar loads, hidden under the BW-bound C
// stream). Nontemporal on the zero-reuse C_prev/C_t stream.
// ---------------------------------------------------------------------------
__global__ __launch_bounds__(256) void c_update(
    const float* __restrict__ C_prev, const float* __restrict__ ws,
    const float* __restrict__ be, const float* __restrict__ n_prev,
    float* __restrict__ h_t, float* __restrict__ C_t,
    float* __restrict__ n_out)
{
    const int t    = threadIdx.x;
    const int lane = t & 63;
    const int w    = t >> 6;                       // wave 0..3
    const int R0   = blockIdx.x * 32 + w * 8;      // first of 8 rows
    const int b    = R0 >> 10;

    const float4* kp = (const float4*)(ws + 3 * BH + (size_t)b * 1024);
    const float4* qp = (const float4*)(ws + 5 * BH + (size_t)b * 1024);
    float4 k4[4], q4[4];
    #pragma unroll
    for (int c = 0; c < 4; ++c) {
        k4[c] = kp[c * 64 + lane];
        q4[c] = qp[c * 64 + lane];
    }

    #pragma unroll 2
    for (int r = 0; r < 8; ++r) {
        const int R    = R0 + r;
        const float f  = ws[1 * BH + R];
        const float i_ = ws[0 * BH + R];
        const float iv = i_ * ws[4 * BH + R];

        // n_t = f*n_prev + i*exp(sum of 16 ngate partials + be)
        float m = be[R & 1023];
        #pragma unroll
        for (int s = 0; s < 16; ++s) m += ws[WS_NP + (size_t)s * BH + R];
        const float n = f * n_prev[R] + i_ * expf(m);

        const v4f* cp = (const v4f*)(C_prev + (size_t)R * 1024);
        v4f*       co = (v4f*)(C_t + (size_t)R * 1024);

        float dot = 0.f;
        #pragma unroll
        for (int c = 0; c < 4; ++c) {
            const v4f c4 = __builtin_nontemporal_load(&cp[c * 64 + lane]);
            v4f o4;
            o4.x = f * c4.x + iv * k4[c].x;
            o4.y = f * c4.y + iv * k4[c].y;
            o4.z = f * c4.z + iv * k4[c].z;
            o4.w = f * c4.w + iv * k4[c].w;
            __builtin_nontemporal_store(o4, &co[c * 64 + lane]);
            dot += o4.x * q4[c].x + o4.y * q4[c].y
                 + o4.z * q4[c].z + o4.w * q4[c].w;
        }
        #pragma unroll
        for (int off = 32; off; off >>= 1)
            dot += __shfl_xor(dot, off);
        if (lane == 0) {
            h_t[R]   = ws[2 * BH + R] * dot / n;
            n_out[R] = n;
        }
    }
}

// ---------------------------------------------------------------------------
extern "C" void kernel_launch(void* const* d_in, const int* in_sizes, int n_in,
                              void* d_out, int out_size, void* d_ws, size_t ws_size,
                              hipStream_t stream)
{
    const float* x      = (const float*)d_in[0];
    const float* h_prev = (const float*)d_in[1];
    const float* C_prev = (const float*)d_in[2];
    const float* n_prev = (const float*)d_in[3];
    const float* Wi = (const float*)d_in[4];  const float* bi = (const float*)d_in[5];
    const float* Wf = (const float*)d_in[6];  const float* bf = (const float*)d_in[7];
    const float* Wo = (const float*)d_in[8];  const float* bo = (const float*)d_in[9];
    const float* Wk = (const float*)d_in[10]; const float* bk = (const float*)d_in[11];
    const float* Wv = (const float*)d_in[12]; const float* bv = (const float*)d_in[13];
    const float* Wq = (const float*)d_in[14]; const float* bq = (const float*)d_in[15];
    const float* We = (const float*)d_in[16]; const float* be = (const float*)d_in[17];

    float* out = (float*)d_out;
    float* h_t = out;                                 // [B,H]
    float* C_t = out + BH;                            // [B,H,H]
    float* n_t = out + BH + (size_t)Bn * Hn * Hn;     // [B,H]
    float* ws  = (float*)d_ws;                        // 70*BH floats (~18 MB)

    gates_partial<<<dim3(16, 8, 6), 256, 0, stream>>>(
        x, h_prev, Wi, Wf, Wo, Wk, Wv, Wq, ws);

    gates_finalize<<<384, 256, 0, stream>>>(
        bi, bf, bo, bk, bv, bq, ws);

    ngate_partial<<<dim3(16, 16), 256, 0, stream>>>(We, ws);

    c_update<<<2048, 256, 0, stream>>>(
        C_prev, ws, be, n_prev, h_t, C_t, n_t);
}